// Round 7
// baseline (512.900 us; speedup 1.0000x reference)
//
#include <hip/hip_runtime.h>
#include <stdint.h>
#include <stddef.h>

// ---------------------------------------------------------------------------
// LongRangeDW: x(8,128,128,128) -> nnstack(5C) -> 3 depthwise (1x1, 3x3 d8,
// 3x3 d12) -> pointwise 5C->C -> +x.
// R7: dw __launch_bounds__(256,1). R6's counters showed a spill (WRITE +64.5MB,
// FETCH +31MB of scratch at VGPR=128): live set at store_pack16 sites ~180 regs
// vs the 128 cap. dw is LDS-bound at 2 blocks/CU (54KB), so VGPR up to 256 is
// residency-free -> uncap. Also gives the scheduler room to double-buffer
// rb[48] across rows (the ds_read->unpack->FMA serialization). Everything else
// identical to R6 (4-plane dw + store_pack16; R4 dbuf gemm; nbc=4).
// ---------------------------------------------------------------------------

static constexpr int Cc  = 128;
static constexpr int C5  = 640;
static constexpr int Hh  = 128;
static constexpr int Ww  = 128;
static constexpr int LC  = 160;          // LDS cols (128 + 16 guard each side)
static constexpr int GR  = 42;           // LDS rows (16 + 13 guard each side)
static constexpr int PSz = GR * LC + 8;  // plane stride (ushort)

typedef __attribute__((ext_vector_type(8))) short short8;
typedef __attribute__((ext_vector_type(4))) float f32x4;

__device__ __forceinline__ uint16_t f2bf(float f) {
  uint32_t b = __float_as_uint(f);
  b += 0x7fffu + ((b >> 16) & 1u);      // RNE
  return (uint16_t)(b >> 16);
}
__device__ __forceinline__ float bflo(uint32_t v) { return __uint_as_float(v << 16); }
__device__ __forceinline__ float bfhi(uint32_t v) { return __uint_as_float(v & 0xffff0000u); }

__device__ __forceinline__ uint32_t cvt_pk_bf16(float a, float b) {
  // D.lo16 = bf16(a), D.hi16 = bf16(b); RNE — bit-identical to f2bf pairs.
  uint32_t r;
  asm("v_cvt_pk_bf16_f32 %0, %1, %2" : "=v"(r) : "v"(a), "v"(b));
  return r;
}

__device__ __forceinline__ void async16(uint16_t* lds, const uint16_t* gm) {
  __builtin_amdgcn_global_load_lds(
      (const __attribute__((address_space(1))) uint32_t*)gm,
      (__attribute__((address_space(3))) uint32_t*)lds, 16, 0, 0);
}

// ---------------------------------------------------------------------------
// store_pack16: lane quad (ce=0..3) holds acc[16] (p = j0..j0+15) for ke=ce.
// Layout wants ushort s = (p - j0)*4 + ke. Transpose across the 4 lanes so
// lane ce stores the 16 contiguous ushorts s in [16*ce, 16*ce+15]
// (p' = 4*ce..4*ce+3, all ke) as two dwordx4 stores. Wave stores full 128B
// lines (quad covers one line).
// ---------------------------------------------------------------------------
__device__ __forceinline__ void store_pack16(uint16_t* __restrict__ dst,
                                             int ce, const float* acc) {
  const bool odd = (ce & 1) != 0;
  const bool hi2 = (ce & 2) != 0;

  // pack p-pairs of own ke: m[j] = (bf(p=2j) lo, bf(p=2j+1) hi)
  uint32_t m[8];
#pragma unroll
  for (int j = 0; j < 8; ++j) m[j] = cvt_pk_bf16(acc[2 * j], acc[2 * j + 1]);

  // rotate by 2*ce: mp[j] = m[(j + 2*ce) & 7]  -> own p-range at slots 0,1
  uint32_t t2[8], mp[8];
#pragma unroll
  for (int j = 0; j < 8; ++j) t2[j] = odd ? m[(j + 2) & 7] : m[j];
#pragma unroll
  for (int j = 0; j < 8; ++j) mp[j] = hi2 ? t2[(j + 4) & 7] : t2[j];

  // exchange with ce^1 (other ke of the ke-pair), slot-aligned to O below
  uint32_t E0 = odd ? mp[6] : mp[2];
  uint32_t E1 = odd ? mp[7] : mp[3];
  uint32_t E2 = odd ? mp[2] : mp[6];
  uint32_t E3 = odd ? mp[3] : mp[7];
  uint32_t R0 = __shfl_xor((int)E0, 1);
  uint32_t R1 = __shfl_xor((int)E1, 1);
  uint32_t R2 = __shfl_xor((int)E2, 1);
  uint32_t R3 = __shfl_xor((int)E3, 1);

  uint32_t O[4] = {mp[0], mp[1], mp[4], mp[5]};
  uint32_t R[4] = {R0, R1, R2, R3};

  // combine into ke-pair dwords: low ushort = lower ke of the pair
  uint32_t Q[8];
#pragma unroll
  for (int t = 0; t < 4; ++t) {
    uint32_t X = odd ? R[t] : O[t];
    uint32_t Y = odd ? O[t] : R[t];
    Q[2 * t]     = (X & 0xffffu) | (Y << 16);
    Q[2 * t + 1] = (X >> 16) | (Y & 0xffff0000u);
  }

  // exchange Q[4..7] with ce^2: receive the other ke-pair at own p-range
  uint32_t S[4];
#pragma unroll
  for (int t = 0; t < 4; ++t) S[t] = __shfl_xor((int)Q[4 + t], 2);

  // interleave: even dword = ke01 pair, odd dword = ke23 pair
  uint32_t D[8];
#pragma unroll
  for (int t = 0; t < 4; ++t) {
    D[2 * t]     = hi2 ? S[t] : Q[t];
    D[2 * t + 1] = hi2 ? Q[t] : S[t];
  }

  uint4 v0 = make_uint4(D[0], D[1], D[2], D[3]);
  uint4 v1 = make_uint4(D[4], D[5], D[6], D[7]);
  *(uint4*)(dst + ce * 16)     = v0;
  *(uint4*)(dst + ce * 16 + 8) = v1;
}

// ---------------------------------------------------------------------------
// prep: w4 -> bf16 [o][k] ; combined dw weights cw2 (center folds w1+w3c),
// cw3 ; bias sums.
// ---------------------------------------------------------------------------
__global__ void prep_kernel(const float* __restrict__ w1, const float* __restrict__ b1,
                            const float* __restrict__ w2, const float* __restrict__ b2,
                            const float* __restrict__ w3, const float* __restrict__ b3,
                            const float* __restrict__ w4,
                            uint16_t* __restrict__ w4b, float* __restrict__ cw2,
                            float* __restrict__ cw3, float* __restrict__ bsum) {
  int i = blockIdx.x * 256 + threadIdx.x;
  if (i < Cc * C5) w4b[i] = f2bf(w4[i]);
  if (i < C5) {
    bsum[i] = b1[i] + b2[i] + b3[i];
#pragma unroll
    for (int t = 0; t < 9; ++t) {
      float a = w2[i * 9 + t];
      if (t == 4) a += w1[i] + w3[i * 9 + 4];
      cw2[i * 9 + t] = a;
      cw3[i * 9 + t] = w3[i * 9 + t];
    }
  }
}

// ---------------------------------------------------------------------------
// dw_kernel: block = (band of 16 rows, c-quad g, batch). 4 x-planes (bf16,
// zero-guarded halo 13 rows / 16 cols) in LDS. Each thread: ce=tid&3, jt strip
// of 16 cols, ir row. Computes all 5 stack-shifts m for its (c,row,strip).
// m order: m0=below(+1,0) m1=above(-1,0) m2=right(0,+1) m3=left(0,-1)
// m4=center.  y layout: [bl][k4=k/4][p=i*128+j][ke=k%4]  (k=m*128+c), bf16.
// ---------------------------------------------------------------------------
__global__ __launch_bounds__(256, 1) void dw_kernel(
    const float* __restrict__ x, const float* __restrict__ cw2,
    const float* __restrict__ cw3, const float* __restrict__ bsum,
    uint16_t* __restrict__ y, int b0) {
  __shared__ uint16_t xs[4 * PSz];    // 53824 B -> 2 blocks/CU (LDS-limited)

  const int band = blockIdx.x;        // 0..7
  const int g    = blockIdx.y;        // 0..31  (c-quad)
  const int bl   = blockIdx.z;        // batch within chunk
  const int bb   = b0 + bl;
  const int i0   = band * 16;
  const int tid  = threadIdx.x;

  // ---- stage x (4 channels) into LDS as bf16 with zero guards ----
  // 4 ch * 42 rows * 40 float4 = 6720 units
#pragma unroll
  for (int it = 0; it < 27; ++it) {
    int idx = it * 256 + tid;
    if (idx < 6720) {
      int col4 = idx % 40;
      int rr   = (idx / 40) % 42;
      int cel  = idx / 1680;          // 0..3
      int gi = i0 - 13 + rr;
      int gj = col4 * 4 - 16;
      float4 v = make_float4(0.f, 0.f, 0.f, 0.f);
      if ((unsigned)gi < 128u && col4 >= 4 && col4 < 36) {
        v = *(const float4*)(x + (((size_t)(bb * Cc + g * 4 + cel) * Hh + gi) << 7) + gj);
      }
      ushort4 h;
      h.x = f2bf(v.x); h.y = f2bf(v.y); h.z = f2bf(v.z); h.w = f2bf(v.w);
      *(ushort4*)(xs + cel * PSz + rr * LC + col4 * 4) = h;
    }
  }
  __syncthreads();

  const int ce = tid & 3;
  const int jt = (tid >> 2) & 7;
  const int ir = tid >> 5;            // 0..7
  const int j0 = jt * 16;
  const int c  = g * 4 + ce;

  float rb[48];
  // rb[e] corresponds to global col j0 - 16 + e ; tap at col offset off for
  // output jj reads rb[16 + off + jj].
#define LOAD_RB(ROW)                                                      \
  do {                                                                    \
    const uint16_t* _p = xs + ce * PSz + (ROW) * LC + j0;                 \
    _Pragma("unroll") for (int _u = 0; _u < 6; ++_u) {                    \
      uint4 _q = *(const uint4*)(_p + _u * 8);                            \
      rb[_u * 8 + 0] = bflo(_q.x); rb[_u * 8 + 1] = bfhi(_q.x);           \
      rb[_u * 8 + 2] = bflo(_q.y); rb[_u * 8 + 3] = bfhi(_q.y);           \
      rb[_u * 8 + 4] = bflo(_q.z); rb[_u * 8 + 5] = bfhi(_q.z);           \
      rb[_u * 8 + 6] = bflo(_q.w); rb[_u * 8 + 7] = bfhi(_q.w);           \
    }                                                                     \
  } while (0)

  // =======================================================================
  // Group A: m4 (center, aj=0), m2 (right, aj=+1), m3 (left, aj=-1).
  // Rows delta in {-12,-8,0,8,12} shared by all three.
  // =======================================================================
  {
    float w2r[3][9], w3r[3][9], bs[3];
    const int msA[3] = {4, 2, 3};
#pragma unroll
    for (int mi = 0; mi < 3; ++mi) {
      int k = msA[mi] * Cc + c;
#pragma unroll
      for (int t = 0; t < 9; ++t) {
        w2r[mi][t] = cw2[k * 9 + t];
        w3r[mi][t] = cw3[k * 9 + t];
      }
      bs[mi] = bsum[k];
    }

#pragma unroll
    for (int it2 = 0; it2 < 2; ++it2) {
      const int i     = i0 + ir + 8 * it2;
      const int rbase = ir + 8 * it2 + 13;
      float acc[3][16];
#pragma unroll
      for (int mi = 0; mi < 3; ++mi)
#pragma unroll
        for (int jj = 0; jj < 16; ++jj) acc[mi][jj] = bs[mi];

#define AROW3(DLT, WARR, UB, DD)                                          \
      do {                                                                \
        LOAD_RB(rbase + (DLT));                                           \
        _Pragma("unroll") for (int mi = 0; mi < 3; ++mi) {                \
          const int aj = (mi == 0) ? 0 : ((mi == 1) ? 1 : -1);            \
          _Pragma("unroll") for (int v = 0; v < 3; ++v) {                 \
            const float w = WARR[mi][(UB) + v];                           \
            const int e = 16 + (DD) * (v - 1) + aj;                       \
            _Pragma("unroll") for (int jj = 0; jj < 16; ++jj)             \
              acc[mi][jj] += w * rb[e + jj];                              \
          }                                                               \
        }                                                                 \
      } while (0)

      AROW3(-12, w3r, 0, 12);
      if (j0 == 0)   acc[1][11] -= w3r[1][0] * rb[16];
      if (j0 == 112) acc[2][4]  -= w3r[2][2] * rb[31];

      AROW3(-8, w2r, 0, 8);
      if (j0 == 0)   acc[1][7]  -= w2r[1][0] * rb[16];
      if (j0 == 112) acc[2][8]  -= w2r[2][2] * rb[31];

      {  // center row: w2 u=1 (3 taps) + w3[3](-12) + w3[5](+12)
        LOAD_RB(rbase);
#pragma unroll
        for (int mi = 0; mi < 3; ++mi) {
          const int aj = (mi == 0) ? 0 : ((mi == 1) ? 1 : -1);
#pragma unroll
          for (int v = 0; v < 3; ++v) {
            const float w = w2r[mi][3 + v];
            const int e = 16 + 8 * (v - 1) + aj;
#pragma unroll
            for (int jj = 0; jj < 16; ++jj) acc[mi][jj] += w * rb[e + jj];
          }
          {
            const float w = w3r[mi][3]; const int e = 4 + aj;
#pragma unroll
            for (int jj = 0; jj < 16; ++jj) acc[mi][jj] += w * rb[e + jj];
          }
          {
            const float w = w3r[mi][5]; const int e = 28 + aj;
#pragma unroll
            for (int jj = 0; jj < 16; ++jj) acc[mi][jj] += w * rb[e + jj];
          }
        }
        if (j0 == 0)   { acc[1][7] -= w2r[1][3] * rb[16]; acc[1][11] -= w3r[1][3] * rb[16]; }
        if (j0 == 112) { acc[2][8] -= w2r[2][5] * rb[31]; acc[2][4]  -= w3r[2][5] * rb[31]; }
      }

      AROW3(8, w2r, 6, 8);
      if (j0 == 0)   acc[1][7]  -= w2r[1][6] * rb[16];
      if (j0 == 112) acc[2][8]  -= w2r[2][8] * rb[31];

      AROW3(12, w3r, 6, 12);
      if (j0 == 0)   acc[1][11] -= w3r[1][6] * rb[16];
      if (j0 == 112) acc[2][4]  -= w3r[2][8] * rb[31];
#undef AROW3

#pragma unroll
      for (int mi = 0; mi < 3; ++mi) {
        const int msA_[3] = {4, 2, 3};
        int k4 = msA_[mi] * 32 + g;
        size_t rowb = (((size_t)(bl * 160 + k4) << 14) + (size_t)i * Ww + j0) * 4;
        store_pack16(y + rowb, ce, acc[mi]);
      }
    }
  }

  // =======================================================================
  // Group B: m0 (below, ai=+1, mask rows where i+dlt==0),
  //          m1 (above, ai=-1, mask rows where i+dlt==127).
  // =======================================================================
  {
    float w2r[2][9], w3r[2][9], bs[2];
#pragma unroll
    for (int mi = 0; mi < 2; ++mi) {
      int k = mi * Cc + c;
#pragma unroll
      for (int t = 0; t < 9; ++t) {
        w2r[mi][t] = cw2[k * 9 + t];
        w3r[mi][t] = cw3[k * 9 + t];
      }
      bs[mi] = bsum[k];
    }

#pragma unroll
    for (int it2 = 0; it2 < 2; ++it2) {
      const int i     = i0 + ir + 8 * it2;
      const int rbase = ir + 8 * it2 + 13;
      float acc[2][16];
#pragma unroll
      for (int mi = 0; mi < 2; ++mi)
#pragma unroll
        for (int jj = 0; jj < 16; ++jj) acc[mi][jj] = bs[mi];

#define BROW3(MI, DLT, WARR, UB, DD, BADROW)                              \
      do {                                                                \
        LOAD_RB(rbase + (DLT));                                           \
        const float sel = ((i + (DLT)) == (BADROW)) ? 0.f : 1.f;          \
        _Pragma("unroll") for (int v = 0; v < 3; ++v) {                   \
          const float w = WARR[MI][(UB) + v] * sel;                       \
          const int e = 16 + (DD) * (v - 1);                              \
          _Pragma("unroll") for (int jj = 0; jj < 16; ++jj)               \
            acc[MI][jj] += w * rb[e + jj];                                \
        }                                                                 \
      } while (0)

#define BROWC(MI, DLT, BADROW)                                            \
      do {                                                                \
        LOAD_RB(rbase + (DLT));                                           \
        const float sel = ((i + (DLT)) == (BADROW)) ? 0.f : 1.f;          \
        _Pragma("unroll") for (int v = 0; v < 3; ++v) {                   \
          const float w = w2r[MI][3 + v] * sel;                           \
          const int e = 16 + 8 * (v - 1);                                 \
          _Pragma("unroll") for (int jj = 0; jj < 16; ++jj)               \
            acc[MI][jj] += w * rb[e + jj];                                \
        }                                                                 \
        {                                                                 \
          const float w = w3r[MI][3] * sel;                               \
          _Pragma("unroll") for (int jj = 0; jj < 16; ++jj)               \
            acc[MI][jj] += w * rb[4 + jj];                                \
        }                                                                 \
        {                                                                 \
          const float w = w3r[MI][5] * sel;                               \
          _Pragma("unroll") for (int jj = 0; jj < 16; ++jj)               \
            acc[MI][jj] += w * rb[28 + jj];                               \
        }                                                                 \
      } while (0)

      // m0: deltas {-11,-7,1,9,13}
      BROW3(0, -11, w3r, 0, 12, 0);
      BROW3(0, -7,  w2r, 0, 8, 0);
      BROWC(0, 1, 0);
      BROW3(0, 9,   w2r, 6, 8, 0);
      BROW3(0, 13,  w3r, 6, 12, 0);
      // m1: deltas {-13,-9,-1,7,11}
      BROW3(1, -13, w3r, 0, 12, 127);
      BROW3(1, -9,  w2r, 0, 8, 127);
      BROWC(1, -1, 127);
      BROW3(1, 7,   w2r, 6, 8, 127);
      BROW3(1, 11,  w3r, 6, 12, 127);
#undef BROW3
#undef BROWC

#pragma unroll
      for (int mi = 0; mi < 2; ++mi) {
        int k4 = mi * 32 + g;
        size_t rowb = (((size_t)(bl * 160 + k4) << 14) + (size_t)i * Ww + j0) * 4;
        store_pack16(y + rowb, ce, acc[mi]);
      }
    }
  }
#undef LOAD_RB
}

// ---------------------------------------------------------------------------
// gemm_kernel: out[b,o,p] = sum_k w4[o,k]*y[b,k,p] + b4[o] + x[b,o,p]
// M=128 (all o), N-tile=128 p, K=640 in 10 tiles of 64.
// Double-buffered LDS: per K-tile, STAGE(next -> other buf) issued BEFORE the
// current tile's ds_reads+MFMAs; single __syncthreads per tile.
// ---------------------------------------------------------------------------
__global__ __launch_bounds__(256, 2) void gemm_kernel(
    const uint16_t* __restrict__ w4b, const uint16_t* __restrict__ y,
    const float* __restrict__ x, const float* __restrict__ b4,
    float* __restrict__ out, int b0) {
  __shared__ uint16_t As[2][128 * 64];     // [buf][o][64 k]      2x16 KiB
  __shared__ uint16_t Bs[2][16 * 128 * 4]; // [buf][k4t][p][ke4]  2x16 KiB

  const int tid  = threadIdx.x;
  const int lane = tid & 63;
  const int wave = tid >> 6;
  const int p0   = blockIdx.x * 128;
  const int bl   = blockIdx.y;
  const int bb   = b0 + bl;

  const int col = lane & 15;
  const int q   = lane >> 4;
  const int o_base = (wave >> 1) * 64;
  const int p_base = (wave & 1) * 64;

  f32x4 acc[4][4];
#pragma unroll
  for (int fm = 0; fm < 4; ++fm)
#pragma unroll
    for (int fn = 0; fn < 4; ++fn) acc[fm][fn] = (f32x4){0.f, 0.f, 0.f, 0.f};

#define STAGE(BUF, KT)                                                      \
  do {                                                                      \
    _Pragma("unroll") for (int l = 0; l < 4; ++l) {                         \
      int u  = (wave * 4 + l) * 64 + lane;                                  \
      int o  = u >> 3, ch = u & 7;                                          \
      async16(As[BUF] + u * 8, w4b + (size_t)o * 640 + (KT) * 64 + ch * 8); \
    }                                                                       \
    _Pragma("unroll") for (int l = 0; l < 4; ++l) {                         \
      int k4t = wave * 4 + l;                                               \
      async16(Bs[BUF] + (k4t * 64 + lane) * 8,                              \
              y + (((size_t)(bl * 160 + (KT) * 16 + k4t) << 14) + p0) * 4   \
                + lane * 8);                                                \
    }                                                                       \
  } while (0)

#define COMPUTE(BUF)                                                        \
  do {                                                                      \
    _Pragma("unroll") for (int kk = 0; kk < 2; ++kk) {                      \
      short8 af[4], bf[4];                                                  \
      _Pragma("unroll") for (int fm = 0; fm < 4; ++fm) {                    \
        int o = o_base + fm * 16 + col;                                     \
        af[fm] = *(const short8*)(As[BUF] + o * 64 + kk * 32 + q * 8);      \
      }                                                                     \
      _Pragma("unroll") for (int fn = 0; fn < 4; ++fn) {                    \
        int p = p_base + fn * 16 + col;                                     \
        union { short8 s; uint32_t u[4]; } bu;                              \
        const uint32_t* lo =                                                \
            (const uint32_t*)(Bs[BUF] + ((kk * 8 + 2 * q) * 128 + p) * 4);  \
        const uint32_t* hi =                                                \
            (const uint32_t*)(Bs[BUF] + ((kk * 8 + 2 * q + 1) * 128 + p) * 4); \
        bu.u[0] = lo[0]; bu.u[1] = lo[1]; bu.u[2] = hi[0]; bu.u[3] = hi[1]; \
        bf[fn] = bu.s;                                                      \
      }                                                                     \
      _Pragma("unroll") for (int fm = 0; fm < 4; ++fm)                      \
        _Pragma("unroll") for (int fn = 0; fn < 4; ++fn)                    \
          acc[fm][fn] = __builtin_amdgcn_mfma_f32_16x16x32_bf16(            \
              af[fm], bf[fn], acc[fm][fn], 0, 0, 0);                        \
    }                                                                       \
  } while (0)

  STAGE(0, 0);
  __syncthreads();

#pragma unroll
  for (int kt = 0; kt < 10; kt += 2) {
    STAGE(1, kt + 1);
    COMPUTE(0);
    __syncthreads();
    if (kt + 2 < 10) STAGE(0, kt + 2);
    COMPUTE(1);
    __syncthreads();
  }
#undef STAGE
#undef COMPUTE

  // epilogue: + b4 + residual x ; C/D layout col=lane&15, row=q*4+r
#pragma unroll
  for (int fm = 0; fm < 4; ++fm) {
#pragma unroll
    for (int fn = 0; fn < 4; ++fn) {
      int pg = p0 + p_base + fn * 16 + col;
#pragma unroll
      for (int r = 0; r < 4; ++r) {
        int oo = o_base + fm * 16 + q * 4 + r;
        size_t oi = ((size_t)(bb * 128 + oo) << 14) + pg;
        out[oi] = acc[fm][fn][r] + b4[oo] + x[oi];
      }
    }
  }
}

// ---------------------------------------------------------------------------
extern "C" void kernel_launch(void* const* d_in, const int* in_sizes, int n_in,
                              void* d_out, int out_size, void* d_ws, size_t ws_size,
                              hipStream_t stream) {
  const float* x  = (const float*)d_in[0];
  const float* w1 = (const float*)d_in[1];
  const float* b1 = (const float*)d_in[2];
  const float* w2 = (const float*)d_in[3];
  const float* b2 = (const float*)d_in[4];
  const float* w3 = (const float*)d_in[5];
  const float* b3 = (const float*)d_in[6];
  const float* w4 = (const float*)d_in[7];
  const float* b4 = (const float*)d_in[8];
  float* out = (float*)d_out;

  char* ws = (char*)d_ws;
  uint16_t* w4b  = (uint16_t*)ws;              // 163840 B
  float*    cw2  = (float*)(ws + 163840);      // 23040 B
  float*    cw3  = (float*)(ws + 186880);      // 23040 B
  float*    bsum = (float*)(ws + 209920);      // 2560 B
  uint16_t* y    = (uint16_t*)(ws + (1 << 20));

  const size_t per_b = (size_t)160 * 16384 * 4 * 2;  // 20 MiB per batch
  int nbc = 4;   // chunk of batches (y ~84MiB -> L3-resident for gemm)
  while (nbc > 1 && (size_t)(1 << 20) + (size_t)nbc * per_b > ws_size) nbc >>= 1;

  hipLaunchKernelGGL(prep_kernel, dim3(320), dim3(256), 0, stream,
                     w1, b1, w2, b2, w3, b3, w4, w4b, cw2, cw3, bsum);
  for (int b0 = 0; b0 < 8; b0 += nbc) {
    int nb = (8 - b0) < nbc ? (8 - b0) : nbc;
    hipLaunchKernelGGL(dw_kernel, dim3(8, 32, nb), dim3(256), 0, stream,
                       x, cw2, cw3, bsum, y, b0);
    hipLaunchKernelGGL(gemm_kernel, dim3(128, nb), dim3(256), 0, stream,
                       w4b, y, x, b4, out, b0);
  }
}

// Round 8
// 332.949 us; speedup vs baseline: 1.5405x; 1.5405x over previous
//
#include <hip/hip_runtime.h>
#include <stdint.h>
#include <stddef.h>

// ---------------------------------------------------------------------------
// LongRangeDW: x(8,128,128,128) -> nnstack(5C) -> 3 depthwise (1x1, 3x3 d8,
// 3x3 d12) -> pointwise 5C->C -> +x.
// R8 = R2 (best measured, 334us) + ONE change: dw pinned to waves_per_eu(2,2).
// Register regime evidence: cap 128 -> spill (R6: +95MB scratch traffic);
// cap 512 via (256,1) -> allocator blew past 256 effective regs -> 1 block/CU
// (R7: occupancy 11.6%, 2.1x slower). Pinning exactly 2 waves/EU gives a
// 256-reg budget (live set ~190 fits spill-free) with a hard >=2-waves floor;
// LDS (54KB) caps at 2 blocks/CU anyway, so extra regs are residency-free and
// let the scheduler double-buffer rb[48] across tap rows (the ds_read->
// unpack->FMA chain every counter set since R2 points at).
// Scalar y-stores kept: R6/R7 proved the 4-lane pack is a per-wave loss
// (stores were never the bottleneck; L2 write-combines the 2B scatter).
// gemm: R2 serial LDS version (best measured, ~63us/dispatch). nbc=4.
// ---------------------------------------------------------------------------

static constexpr int Cc  = 128;
static constexpr int C5  = 640;
static constexpr int Hh  = 128;
static constexpr int Ww  = 128;
static constexpr int LC  = 160;          // LDS cols (128 + 16 guard each side)
static constexpr int GR  = 42;           // LDS rows (16 + 13 guard each side)
static constexpr int PSz = GR * LC + 8;  // plane stride (ushort), +8 keeps 16B align + bank skew

typedef __attribute__((ext_vector_type(8))) short short8;
typedef __attribute__((ext_vector_type(4))) float f32x4;

__device__ __forceinline__ uint16_t f2bf(float f) {
  uint32_t b = __float_as_uint(f);
  b += 0x7fffu + ((b >> 16) & 1u);      // RNE
  return (uint16_t)(b >> 16);
}
__device__ __forceinline__ float bflo(uint32_t v) { return __uint_as_float(v << 16); }
__device__ __forceinline__ float bfhi(uint32_t v) { return __uint_as_float(v & 0xffff0000u); }

__device__ __forceinline__ void async16(uint16_t* lds, const uint16_t* gm) {
  __builtin_amdgcn_global_load_lds(
      (const __attribute__((address_space(1))) uint32_t*)gm,
      (__attribute__((address_space(3))) uint32_t*)lds, 16, 0, 0);
}

// ---------------------------------------------------------------------------
// prep: w4 -> bf16 [o][k] ; combined dw weights cw2 (center folds w1+w3c),
// cw3 ; bias sums.
// ---------------------------------------------------------------------------
__global__ void prep_kernel(const float* __restrict__ w1, const float* __restrict__ b1,
                            const float* __restrict__ w2, const float* __restrict__ b2,
                            const float* __restrict__ w3, const float* __restrict__ b3,
                            const float* __restrict__ w4,
                            uint16_t* __restrict__ w4b, float* __restrict__ cw2,
                            float* __restrict__ cw3, float* __restrict__ bsum) {
  int i = blockIdx.x * 256 + threadIdx.x;
  if (i < Cc * C5) w4b[i] = f2bf(w4[i]);
  if (i < C5) {
    bsum[i] = b1[i] + b2[i] + b3[i];
#pragma unroll
    for (int t = 0; t < 9; ++t) {
      float a = w2[i * 9 + t];
      if (t == 4) a += w1[i] + w3[i * 9 + 4];
      cw2[i * 9 + t] = a;
      cw3[i * 9 + t] = w3[i * 9 + t];
    }
  }
}

// ---------------------------------------------------------------------------
// dw_kernel: block = (band of 16 rows, c-quad g, batch). 4 x-planes (bf16,
// zero-guarded halo 13 rows / 16 cols) in LDS. Each thread: ce=tid&3, jt strip
// of 16 cols, ir row. Computes all 5 stack-shifts m for its (c,row,strip).
// m order (concat order): m0=below(+1,0) m1=above(-1,0) m2=right(0,+1)
// m3=left(0,-1) m4=center.
// y layout: [bl][k4 = k/4][p=i*128+j][ke = k%4]  (k = m*128+c), bf16.
// ---------------------------------------------------------------------------
__global__ __launch_bounds__(256)
__attribute__((amdgpu_waves_per_eu(2, 2)))
void dw_kernel(
    const float* __restrict__ x, const float* __restrict__ cw2,
    const float* __restrict__ cw3, const float* __restrict__ bsum,
    uint16_t* __restrict__ y, int b0) {
  __shared__ uint16_t xs[4 * PSz];    // 53824 B -> 2 blocks/CU (LDS-limited)

  const int band = blockIdx.x;        // 0..7
  const int g    = blockIdx.y;        // 0..31  (c-quad)
  const int bl   = blockIdx.z;        // batch within chunk
  const int bb   = b0 + bl;
  const int i0   = band * 16;
  const int tid  = threadIdx.x;

  // ---- stage x (4 channels) into LDS as bf16 with zero guards ----
  // 4 ch * 42 rows * 40 float4 = 6720 units
#pragma unroll
  for (int it = 0; it < 27; ++it) {
    int idx = it * 256 + tid;
    if (idx < 6720) {
      int col4 = idx % 40;
      int rr   = (idx / 40) % 42;
      int cel  = idx / 1680;          // 0..3
      int gi = i0 - 13 + rr;
      int gj = col4 * 4 - 16;
      float4 v = make_float4(0.f, 0.f, 0.f, 0.f);
      if ((unsigned)gi < 128u && col4 >= 4 && col4 < 36) {
        v = *(const float4*)(x + (((size_t)(bb * Cc + g * 4 + cel) * Hh + gi) << 7) + gj);
      }
      ushort4 h;
      h.x = f2bf(v.x); h.y = f2bf(v.y); h.z = f2bf(v.z); h.w = f2bf(v.w);
      *(ushort4*)(xs + cel * PSz + rr * LC + col4 * 4) = h;
    }
  }
  __syncthreads();

  const int ce = tid & 3;
  const int jt = (tid >> 2) & 7;
  const int ir = tid >> 5;            // 0..7
  const int j0 = jt * 16;
  const int c  = g * 4 + ce;

  float rb[48];
  // rb[e] corresponds to global col j0 - 16 + e ; tap at col offset off for
  // output jj reads rb[16 + off + jj].
#define LOAD_RB(ROW)                                                      \
  do {                                                                    \
    const uint16_t* _p = xs + ce * PSz + (ROW) * LC + j0;                 \
    _Pragma("unroll") for (int _u = 0; _u < 6; ++_u) {                    \
      uint4 _q = *(const uint4*)(_p + _u * 8);                            \
      rb[_u * 8 + 0] = bflo(_q.x); rb[_u * 8 + 1] = bfhi(_q.x);           \
      rb[_u * 8 + 2] = bflo(_q.y); rb[_u * 8 + 3] = bfhi(_q.y);           \
      rb[_u * 8 + 4] = bflo(_q.z); rb[_u * 8 + 5] = bfhi(_q.z);           \
      rb[_u * 8 + 6] = bflo(_q.w); rb[_u * 8 + 7] = bfhi(_q.w);           \
    }                                                                     \
  } while (0)

  // =======================================================================
  // Group A: m4 (center, aj=0), m2 (right, aj=+1), m3 (left, aj=-1).
  // Rows delta in {-12,-8,0,8,12} shared by all three.
  // =======================================================================
  {
    float w2r[3][9], w3r[3][9], bs[3];
    const int msA[3] = {4, 2, 3};
#pragma unroll
    for (int mi = 0; mi < 3; ++mi) {
      int k = msA[mi] * Cc + c;
#pragma unroll
      for (int t = 0; t < 9; ++t) {
        w2r[mi][t] = cw2[k * 9 + t];
        w3r[mi][t] = cw3[k * 9 + t];
      }
      bs[mi] = bsum[k];
    }

#pragma unroll
    for (int it2 = 0; it2 < 2; ++it2) {
      const int i     = i0 + ir + 8 * it2;
      const int rbase = ir + 8 * it2 + 13;
      float acc[3][16];
#pragma unroll
      for (int mi = 0; mi < 3; ++mi)
#pragma unroll
        for (int jj = 0; jj < 16; ++jj) acc[mi][jj] = bs[mi];

#define AROW3(DLT, WARR, UB, DD)                                          \
      do {                                                                \
        LOAD_RB(rbase + (DLT));                                           \
        _Pragma("unroll") for (int mi = 0; mi < 3; ++mi) {                \
          const int aj = (mi == 0) ? 0 : ((mi == 1) ? 1 : -1);            \
          _Pragma("unroll") for (int v = 0; v < 3; ++v) {                 \
            const float w = WARR[mi][(UB) + v];                           \
            const int e = 16 + (DD) * (v - 1) + aj;                       \
            _Pragma("unroll") for (int jj = 0; jj < 16; ++jj)             \
              acc[mi][jj] += w * rb[e + jj];                              \
          }                                                               \
        }                                                                 \
      } while (0)

      AROW3(-12, w3r, 0, 12);
      if (j0 == 0)   acc[1][11] -= w3r[1][0] * rb[16];
      if (j0 == 112) acc[2][4]  -= w3r[2][2] * rb[31];

      AROW3(-8, w2r, 0, 8);
      if (j0 == 0)   acc[1][7]  -= w2r[1][0] * rb[16];
      if (j0 == 112) acc[2][8]  -= w2r[2][2] * rb[31];

      {  // center row: w2 u=1 (3 taps) + w3[3](-12) + w3[5](+12)
        LOAD_RB(rbase);
#pragma unroll
        for (int mi = 0; mi < 3; ++mi) {
          const int aj = (mi == 0) ? 0 : ((mi == 1) ? 1 : -1);
#pragma unroll
          for (int v = 0; v < 3; ++v) {
            const float w = w2r[mi][3 + v];
            const int e = 16 + 8 * (v - 1) + aj;
#pragma unroll
            for (int jj = 0; jj < 16; ++jj) acc[mi][jj] += w * rb[e + jj];
          }
          {
            const float w = w3r[mi][3]; const int e = 4 + aj;
#pragma unroll
            for (int jj = 0; jj < 16; ++jj) acc[mi][jj] += w * rb[e + jj];
          }
          {
            const float w = w3r[mi][5]; const int e = 28 + aj;
#pragma unroll
            for (int jj = 0; jj < 16; ++jj) acc[mi][jj] += w * rb[e + jj];
          }
        }
        if (j0 == 0)   { acc[1][7] -= w2r[1][3] * rb[16]; acc[1][11] -= w3r[1][3] * rb[16]; }
        if (j0 == 112) { acc[2][8] -= w2r[2][5] * rb[31]; acc[2][4]  -= w3r[2][5] * rb[31]; }
      }

      AROW3(8, w2r, 6, 8);
      if (j0 == 0)   acc[1][7]  -= w2r[1][6] * rb[16];
      if (j0 == 112) acc[2][8]  -= w2r[2][8] * rb[31];

      AROW3(12, w3r, 6, 12);
      if (j0 == 0)   acc[1][11] -= w3r[1][6] * rb[16];
      if (j0 == 112) acc[2][4]  -= w3r[2][8] * rb[31];
#undef AROW3

#pragma unroll
      for (int mi = 0; mi < 3; ++mi) {
        const int msA_[3] = {4, 2, 3};
        int k4 = msA_[mi] * 32 + g;
        size_t base = (((size_t)(bl * 160 + k4) << 14) + (size_t)i * Ww + j0) * 4 + ce;
#pragma unroll
        for (int jj = 0; jj < 16; ++jj) y[base + jj * 4] = f2bf(acc[mi][jj]);
      }
    }
  }

  // =======================================================================
  // Group B: m0 (below, ai=+1, mask rows where i+dlt==0),
  //          m1 (above, ai=-1, mask rows where i+dlt==127).
  // =======================================================================
  {
    float w2r[2][9], w3r[2][9], bs[2];
#pragma unroll
    for (int mi = 0; mi < 2; ++mi) {
      int k = mi * Cc + c;
#pragma unroll
      for (int t = 0; t < 9; ++t) {
        w2r[mi][t] = cw2[k * 9 + t];
        w3r[mi][t] = cw3[k * 9 + t];
      }
      bs[mi] = bsum[k];
    }

#pragma unroll
    for (int it2 = 0; it2 < 2; ++it2) {
      const int i     = i0 + ir + 8 * it2;
      const int rbase = ir + 8 * it2 + 13;
      float acc[2][16];
#pragma unroll
      for (int mi = 0; mi < 2; ++mi)
#pragma unroll
        for (int jj = 0; jj < 16; ++jj) acc[mi][jj] = bs[mi];

#define BROW3(MI, DLT, WARR, UB, DD, BADROW)                              \
      do {                                                                \
        LOAD_RB(rbase + (DLT));                                           \
        const float sel = ((i + (DLT)) == (BADROW)) ? 0.f : 1.f;          \
        _Pragma("unroll") for (int v = 0; v < 3; ++v) {                   \
          const float w = WARR[MI][(UB) + v] * sel;                       \
          const int e = 16 + (DD) * (v - 1);                              \
          _Pragma("unroll") for (int jj = 0; jj < 16; ++jj)               \
            acc[MI][jj] += w * rb[e + jj];                                \
        }                                                                 \
      } while (0)

#define BROWC(MI, DLT, BADROW)                                            \
      do {                                                                \
        LOAD_RB(rbase + (DLT));                                           \
        const float sel = ((i + (DLT)) == (BADROW)) ? 0.f : 1.f;          \
        _Pragma("unroll") for (int v = 0; v < 3; ++v) {                   \
          const float w = w2r[MI][3 + v] * sel;                           \
          const int e = 16 + 8 * (v - 1);                                 \
          _Pragma("unroll") for (int jj = 0; jj < 16; ++jj)               \
            acc[MI][jj] += w * rb[e + jj];                                \
        }                                                                 \
        {                                                                 \
          const float w = w3r[MI][3] * sel;                               \
          _Pragma("unroll") for (int jj = 0; jj < 16; ++jj)               \
            acc[MI][jj] += w * rb[4 + jj];                                \
        }                                                                 \
        {                                                                 \
          const float w = w3r[MI][5] * sel;                               \
          _Pragma("unroll") for (int jj = 0; jj < 16; ++jj)               \
            acc[MI][jj] += w * rb[28 + jj];                               \
        }                                                                 \
      } while (0)

      // m0: deltas {-11,-7,1,9,13}
      BROW3(0, -11, w3r, 0, 12, 0);
      BROW3(0, -7,  w2r, 0, 8, 0);
      BROWC(0, 1, 0);
      BROW3(0, 9,   w2r, 6, 8, 0);
      BROW3(0, 13,  w3r, 6, 12, 0);
      // m1: deltas {-13,-9,-1,7,11}
      BROW3(1, -13, w3r, 0, 12, 127);
      BROW3(1, -9,  w2r, 0, 8, 127);
      BROWC(1, -1, 127);
      BROW3(1, 7,   w2r, 6, 8, 127);
      BROW3(1, 11,  w3r, 6, 12, 127);
#undef BROW3
#undef BROWC

#pragma unroll
      for (int mi = 0; mi < 2; ++mi) {
        int k4 = mi * 32 + g;
        size_t base = (((size_t)(bl * 160 + k4) << 14) + (size_t)i * Ww + j0) * 4 + ce;
#pragma unroll
        for (int jj = 0; jj < 16; ++jj) y[base + jj * 4] = f2bf(acc[mi][jj]);
      }
    }
  }
#undef LOAD_RB
}

// ---------------------------------------------------------------------------
// gemm_kernel (R2): out[b,o,p] = sum_k w4[o,k]*y[b,k,p] + b4[o] + x[b,o,p]
// M=128 (all o), N-tile=128 p, K=640 in 10 tiles of 64.
// A = w4b bf16 [o][640]; B = y [bl][k4][p][4] bf16. MFMA 16x16x32 bf16.
// ---------------------------------------------------------------------------
__global__ __launch_bounds__(256, 2) void gemm_kernel(
    const uint16_t* __restrict__ w4b, const uint16_t* __restrict__ y,
    const float* __restrict__ x, const float* __restrict__ b4,
    float* __restrict__ out, int b0) {
  __shared__ uint16_t As[128 * 64];     // [o][64 k]      16 KiB
  __shared__ uint16_t Bs[16 * 128 * 4]; // [k4t][p][ke4]  16 KiB

  const int tid  = threadIdx.x;
  const int lane = tid & 63;
  const int wave = tid >> 6;
  const int p0   = blockIdx.x * 128;
  const int bl   = blockIdx.y;
  const int bb   = b0 + bl;

  const int col = lane & 15;
  const int q   = lane >> 4;
  const int o_base = (wave >> 1) * 64;
  const int p_base = (wave & 1) * 64;

  f32x4 acc[4][4];
#pragma unroll
  for (int fm = 0; fm < 4; ++fm)
#pragma unroll
    for (int fn = 0; fn < 4; ++fn) acc[fm][fn] = (f32x4){0.f, 0.f, 0.f, 0.f};

  for (int kt = 0; kt < 10; ++kt) {
    // stage A (1024 x 16B units) and B (1024 x 16B units)
#pragma unroll
    for (int l = 0; l < 4; ++l) {
      int u  = (wave * 4 + l) * 64 + lane;
      int o  = u >> 3, ch = u & 7;
      async16(As + u * 8, w4b + (size_t)o * 640 + kt * 64 + ch * 8);
    }
#pragma unroll
    for (int l = 0; l < 4; ++l) {
      int k4t = wave * 4 + l;
      async16(Bs + (k4t * 64 + lane) * 8,
              y + (((size_t)(bl * 160 + kt * 16 + k4t) << 14) + p0) * 4 + lane * 8);
    }
    __syncthreads();

#pragma unroll
    for (int kk = 0; kk < 2; ++kk) {
      short8 af[4], bf[4];
#pragma unroll
      for (int fm = 0; fm < 4; ++fm) {
        int o = o_base + fm * 16 + col;
        af[fm] = *(const short8*)(As + o * 64 + kk * 32 + q * 8);
      }
#pragma unroll
      for (int fn = 0; fn < 4; ++fn) {
        int p = p_base + fn * 16 + col;
        union { short8 s; uint32_t u[4]; } bu;
        const uint32_t* lo = (const uint32_t*)(Bs + ((kk * 8 + 2 * q) * 128 + p) * 4);
        const uint32_t* hi = (const uint32_t*)(Bs + ((kk * 8 + 2 * q + 1) * 128 + p) * 4);
        bu.u[0] = lo[0]; bu.u[1] = lo[1]; bu.u[2] = hi[0]; bu.u[3] = hi[1];
        bf[fn] = bu.s;
      }
#pragma unroll
      for (int fm = 0; fm < 4; ++fm)
#pragma unroll
        for (int fn = 0; fn < 4; ++fn)
          acc[fm][fn] = __builtin_amdgcn_mfma_f32_16x16x32_bf16(af[fm], bf[fn], acc[fm][fn], 0, 0, 0);
    }
    __syncthreads();
  }

  // epilogue: + b4 + residual x ; C/D layout col=lane&15, row=q*4+r
#pragma unroll
  for (int fm = 0; fm < 4; ++fm) {
#pragma unroll
    for (int fn = 0; fn < 4; ++fn) {
      int pg = p0 + p_base + fn * 16 + col;
#pragma unroll
      for (int r = 0; r < 4; ++r) {
        int oo = o_base + fm * 16 + q * 4 + r;
        size_t oi = ((size_t)(bb * 128 + oo) << 14) + pg;
        out[oi] = acc[fm][fn][r] + b4[oo] + x[oi];
      }
    }
  }
}

// ---------------------------------------------------------------------------
extern "C" void kernel_launch(void* const* d_in, const int* in_sizes, int n_in,
                              void* d_out, int out_size, void* d_ws, size_t ws_size,
                              hipStream_t stream) {
  const float* x  = (const float*)d_in[0];
  const float* w1 = (const float*)d_in[1];
  const float* b1 = (const float*)d_in[2];
  const float* w2 = (const float*)d_in[3];
  const float* b2 = (const float*)d_in[4];
  const float* w3 = (const float*)d_in[5];
  const float* b3 = (const float*)d_in[6];
  const float* w4 = (const float*)d_in[7];
  const float* b4 = (const float*)d_in[8];
  float* out = (float*)d_out;

  char* ws = (char*)d_ws;
  uint16_t* w4b  = (uint16_t*)ws;              // 163840 B
  float*    cw2  = (float*)(ws + 163840);      // 23040 B
  float*    cw3  = (float*)(ws + 186880);      // 23040 B
  float*    bsum = (float*)(ws + 209920);      // 2560 B
  uint16_t* y    = (uint16_t*)(ws + (1 << 20));

  const size_t per_b = (size_t)160 * 16384 * 4 * 2;  // 20 MiB per batch
  int nbc = 4;                                        // chunk of batches (y ~84MiB -> L3)
  while (nbc > 1 && (size_t)(1 << 20) + (size_t)nbc * per_b > ws_size) nbc >>= 1;

  hipLaunchKernelGGL(prep_kernel, dim3(320), dim3(256), 0, stream,
                     w1, b1, w2, b2, w3, b3, w4, w4b, cw2, cw3, bsum);
  for (int b0 = 0; b0 < 8; b0 += nbc) {
    int nb = (8 - b0) < nbc ? (8 - b0) : nbc;
    hipLaunchKernelGGL(dw_kernel, dim3(8, 32, nb), dim3(256), 0, stream,
                       x, cw2, cw3, bsum, y, b0);
    hipLaunchKernelGGL(gemm_kernel, dim3(128, nb), dim3(256), 0, stream,
                       w4b, y, x, b4, out, b0);
  }
}